// Round 9
// baseline (328.346 us; speedup 1.0000x reference)
//
#include <hip/hip_runtime.h>

// B=2, L=2048, D=1024, H=16, HD=64.  All matmuls via bf16 MFMA (fp32 accum).
#define Bc 2
#define Lc 2048
#define Dc 1024
#define Hc 16
#define HDc 64
#define LOG2E 1.44269504088896340736f

typedef __bf16 bf16x8 __attribute__((ext_vector_type(8)));
typedef __bf16 bf16x2 __attribute__((ext_vector_type(2)));
typedef float f32x4 __attribute__((ext_vector_type(4)));
typedef unsigned short u16;
typedef unsigned int u32;
typedef unsigned long long u64;

// fp32 -> bf16 round-to-nearest-even
__device__ __forceinline__ u16 f2bf(float x) {
    union { float f; u32 u; } c; c.f = x;
    u32 u = c.u + 0x7fffu + ((c.u >> 16) & 1u);
    return (u16)(u >> 16);
}

// pack two fp32 -> bf16x2 in one u32 (low = a)
__device__ __forceinline__ u32 pkbf(float a, float b) {
#if __has_builtin(__builtin_amdgcn_cvt_pk_bf16_f32)
    union { bf16x2 v; u32 u; } c;
    c.v = __builtin_amdgcn_cvt_pk_bf16_f32(a, b);
    return c.u;
#else
    return (u32)f2bf(a) | ((u32)f2bf(b) << 16);
#endif
}

// async global->LDS, 16B/lane. LDS dest = wave-uniform base + lane*16 (m104).
__device__ __forceinline__ void g2l16(const void* g, void* l) {
    __builtin_amdgcn_global_load_lds(
        (const __attribute__((address_space(1))) void*)g,
        (__attribute__((address_space(3))) void*)l, 16, 0, 0);
}

// ---------------------------------------------------------------------------
// cast fp32 -> bf16: query (4096x1024) + Wq/Wk/Wv/Wo (1024x1024 each)
// ---------------------------------------------------------------------------
__global__ __launch_bounds__(256) void cast_bf16(
    const float* __restrict__ x,
    const float* __restrict__ wq, const float* __restrict__ wk,
    const float* __restrict__ wv, const float* __restrict__ wo,
    u16* __restrict__ xb, u16* __restrict__ wqb, u16* __restrict__ wkb,
    u16* __restrict__ wvb, u16* __restrict__ wob)
{
    const int i = blockIdx.x * 256 + threadIdx.x;   // float4 index
    const float* s; u16* d; int off;
    if (i < 1048576) { s = x; d = xb; off = i; }
    else {
        const int j = i - 1048576;
        const int sel = j >> 18;            // 0..3
        off = j & 262143;
        s = sel == 0 ? wq : sel == 1 ? wk : sel == 2 ? wv : wo;
        d = sel == 0 ? wqb : sel == 1 ? wkb : sel == 2 ? wvb : wob;
    }
    const float4 f = ((const float4*)s)[off];
    ushort4 o;
    o.x = f2bf(f.x); o.y = f2bf(f.y); o.z = f2bf(f.z); o.w = f2bf(f.w);
    ((ushort4*)d)[off] = o;
}

// ---------------------------------------------------------------------------
// 128x128-tile bf16 NT GEMM body, BK=64, XOR-swizzled staging (R8, frozen).
// ---------------------------------------------------------------------------
__device__ __forceinline__ void gemm128_body(
    const u16* __restrict__ A, const u16* __restrict__ Bm,
    int row0, int col0, int K,
    f32x4 (&acc)[4][4], u16* As, u16* Bs)
{
    const int tid  = threadIdx.x;
    const int w    = tid >> 6;
    const int lane = tid & 63;
    const int l15  = lane & 15, quad = lane >> 4;
    const int srow = lane >> 3;                    // 0..7 row within 8-row chunk
    const int sxor = ((lane & 7) ^ srow) << 3;     // swizzled 16B unit (u16 idx)
    const int wm   = (w & 1) << 6, wn = (w >> 1) << 6;
    const int l7   = l15 & 7;

    for (int k0 = 0; k0 < K; k0 += 64) {
        __syncthreads();                   // prior tile's readers done
#pragma unroll
        for (int s = 0; s < 4; ++s) {      // wave w stages rows [w*32, w*32+32)
            const int rb = w * 32 + s * 8;
            g2l16(&A [(size_t)(row0 + rb + srow) * K + k0 + sxor], &As[rb * 64]);
            g2l16(&Bm[(size_t)(col0 + rb + srow) * K + k0 + sxor], &Bs[rb * 64]);
        }
        __syncthreads();                   // vmcnt(0) drain before use

#pragma unroll
        for (int kk = 0; kk < 2; ++kk) {
            bf16x8 af[4], bf[4];
#pragma unroll
            for (int i = 0; i < 4; ++i)
                af[i] = *(const bf16x8*)&As[(wm + i * 16 + l15) * 64 +
                                            (((kk * 4 + quad) ^ l7) << 3)];
#pragma unroll
            for (int j = 0; j < 4; ++j)
                bf[j] = *(const bf16x8*)&Bs[(wn + j * 16 + l15) * 64 +
                                            (((kk * 4 + quad) ^ l7) << 3)];
#pragma unroll
            for (int i = 0; i < 4; ++i)
#pragma unroll
                for (int j = 0; j < 4; ++j)
                    acc[i][j] = __builtin_amdgcn_mfma_f32_16x16x32_bf16(
                        af[i], bf[j], acc[i][j], 0, 0, 0);
        }
    }
}

// ---------------------------------------------------------------------------
// Fused QKV projection (R8, frozen). grid (32, 8, 3): z selects {q,k,v}.
//   q/k: SWAPPED (A=W, B=X): regs = features -> (B,H,L,HD) contiguous hd.
//   v:   NORMAL  (A=X, B=Wv): regs = tokens -> (B,H,HD,L) contiguous l.
// q: *(0.125*log2e) folded (exp2-domain softmax).
// ---------------------------------------------------------------------------
__global__ __launch_bounds__(256) void gemm_qkv_bf16(
    const u16* __restrict__ Xb,
    const u16* __restrict__ Wqb, const u16* __restrict__ Wkb, const u16* __restrict__ Wvb,
    const float* __restrict__ bq, const float* __restrict__ bk, const float* __restrict__ bv,
    u16* __restrict__ qo, u16* __restrict__ ko, u16* __restrict__ vto)
{
    __shared__ __attribute__((aligned(16))) u16 As[128 * 64];
    __shared__ __attribute__((aligned(16))) u16 Bs[128 * 64];

    const int z = blockIdx.z;
    const int tid = threadIdx.x;
    const int w = tid >> 6, lane = tid & 63;
    const int l15 = lane & 15, quad = lane >> 4;
    const int wm = (w & 1) << 6, wn = (w >> 1) << 6;

    f32x4 acc[4][4];
#pragma unroll
    for (int i = 0; i < 4; ++i)
#pragma unroll
        for (int j = 0; j < 4; ++j)
#pragma unroll
            for (int r = 0; r < 4; ++r) acc[i][j][r] = 0.0f;

    if (z == 2) {
        // ---- v, NORMAL: A = X (tokens), B = Wv (features) ----
        const int row0 = blockIdx.x << 7;      // token tile
        const int col0 = blockIdx.y << 7;      // feature tile
        gemm128_body(Xb, Wvb, row0, col0, Dc, acc, As, Bs);

        const int b = row0 >> 11;              // 128-tile never crosses b
#pragma unroll
        for (int j = 0; j < 4; ++j) {
            const int n = col0 + wn + j * 16 + l15;   // feature
            const float bj = bv[n];
            const int hh = n >> 6, hd = n & 63;
            u16* vbase = vto + (((size_t)(b * Hc + hh) * HDc + hd) << 11);
#pragma unroll
            for (int i = 0; i < 4; ++i) {
                const int l = (row0 + wm + i * 16 + quad * 4) & (Lc - 1);
                uint2 pr;
                pr.x = pkbf(acc[i][j][0] + bj, acc[i][j][1] + bj);
                pr.y = pkbf(acc[i][j][2] + bj, acc[i][j][3] + bj);
                *(uint2*)&vbase[l] = pr;
            }
        }
        return;
    }

    // ---- q/k, SWAPPED: A = W (features), B = X (tokens) ----
    const u16*   W    = z == 0 ? Wqb : Wkb;
    const float* bias = z == 0 ? bq  : bk;
    u16*         outp = z == 0 ? qo  : ko;
    const int row0 = blockIdx.y << 7;          // feature tile
    const int col0 = blockIdx.x << 7;          // token tile
    gemm128_body(W, Xb, row0, col0, Dc, acc, As, Bs);

    const float qs = z == 0 ? 0.125f * LOG2E : 1.0f;   // HD^-0.5 * log2(e)
    const int h = (row0 + wm) >> 6;            // head const per quadrant
    float4 b4[4];
#pragma unroll
    for (int i = 0; i < 4; ++i)
        b4[i] = *(const float4*)&bias[row0 + wm + i * 16 + quad * 4];

#pragma unroll
    for (int j = 0; j < 4; ++j) {
        const int tok = col0 + wn + j * 16 + l15;
        const int bb = tok >> 11, ll = tok & (Lc - 1);
        u16* obase = outp + (((size_t)(bb * Hc + h) * Lc + ll) << 6);
#pragma unroll
        for (int i = 0; i < 4; ++i) {
            uint2 pr;
            pr.x = pkbf((acc[i][j][0] + b4[i].x) * qs, (acc[i][j][1] + b4[i].y) * qs);
            pr.y = pkbf((acc[i][j][2] + b4[i].z) * qs, (acc[i][j][3] + b4[i].w) * qs);
            *(uint2*)&obase[i * 16 + quad * 4] = pr;   // hd = i*16+quad*4
        }
    }
}

// ---------------------------------------------------------------------------
// Flash attention, S^T formulation, max-free softmax.
// R9: LDS-FREE, BARRIER-FREE. R6/R7 showed the per-iter __syncthreads pair
// phase-locks all waves (MfmaUtil 17% + VALUBusy 64% ~ alternate, never
// overlap; pipe-demand sum ~25us vs 81us measured). Every MFMA operand has a
// direct global layout matching its fragment:
//   K-frag (A-op):  16B at k[(kt+t*16+l15)*64 + half*32 + quad*8]
//   Vt-frag (A-op, permuted-k to match pf): two 8B at
//                   vt[(dt*16+l15)*2048 + kt + cp*32 + quad*4 (+16)]
//   Q (B-op) and P (B-op, permuted-k) live in registers.
// No LDS, no __syncthreads: waves free-run and de-phase; per m114 separate
// waves co-issue MFMA+VALU. K/V re-read per wave is L2-absorbed (~20 TB/s
// demand < 34.5 ceiling; bh-fastest swizzle keeps (b,h) on one XCD).
// ---------------------------------------------------------------------------
__global__ __launch_bounds__(256) void attn_mfma(
    const u16* __restrict__ q, const u16* __restrict__ k,
    const u16* __restrict__ vt, u16* __restrict__ out)
{
    const int tid = threadIdx.x;
    const int w = tid >> 6, lane = tid & 63;
    const int l15 = lane & 15, quad = lane >> 4;
    const int bh = blockIdx.x & 31;          // bh fastest: same-bh -> same XCD
    const int qt = blockIdx.x >> 5;          // 0..15
    const int h  = bh & (Hc - 1);
    const int b  = bh >> 4;
    const int l0 = qt << 7;                  // 128 q-rows per block

    const size_t bhs = (size_t)(b * Hc + h) * (Lc * HDc);
    const u16* qb = q  + bhs;
    const u16* kb = k  + bhs;
    const u16* vb = vt + bhs;            // [HD][L]

    // Q B-operand fragments (n = q-row = l15, k = quad*8+i), whole kernel
    bf16x8 qf[2][2];
#pragma unroll
    for (int mt = 0; mt < 2; ++mt) {
        const size_t row = (size_t)(l0 + w * 32 + mt * 16 + l15) * HDc;
        qf[mt][0] = *(const bf16x8*)&qb[row + quad * 8];
        qf[mt][1] = *(const bf16x8*)&qb[row + 32 + quad * 8];
    }

    // lane-invariant base offsets
    const u16* kbase = kb + (size_t)l15 * HDc + quad * 8;   // + (kt+t*16)*HDc
    const u16* vbase = vb + (size_t)l15 * Lc + quad * 4;    // + dt*16*Lc + kt + cp*32

    f32x4 oacc[2][4];
    float l_i[2] = {0.0f, 0.0f};
#pragma unroll
    for (int mt = 0; mt < 2; ++mt)
#pragma unroll
        for (int dt = 0; dt < 4; ++dt)
#pragma unroll
            for (int r = 0; r < 4; ++r) oacc[mt][dt][r] = 0.0f;

    for (int kt = 0; kt < Lc; kt += 64) {
        // ---- direct global->VGPR fragment loads (vmcnt-scheduled) ----
        bf16x8 kf[2][4];
#pragma unroll
        for (int t = 0; t < 4; ++t) {
            const u16* kr = kbase + (size_t)(kt + t * 16) * HDc;
            kf[0][t] = *(const bf16x8*)kr;
            kf[1][t] = *(const bf16x8*)(kr + 32);
        }
        union { bf16x8 v; u64 d[2]; } vf[2][4];
#pragma unroll
        for (int dt = 0; dt < 4; ++dt) {
            const u16* vr = vbase + (size_t)(dt * 16) * Lc + kt;
#pragma unroll
            for (int cp = 0; cp < 2; ++cp) {
                vf[cp][dt].d[0] = *(const u64*)(vr + cp * 32);
                vf[cp][dt].d[1] = *(const u64*)(vr + cp * 32 + 16);
            }
        }

        // ---- S^T = K.Q^T : 4 j-tiles x 2 m-tiles ----
        f32x4 st[2][4];
#pragma unroll
        for (int t = 0; t < 4; ++t)
#pragma unroll
            for (int mt = 0; mt < 2; ++mt) {
                f32x4 z = {0.0f, 0.0f, 0.0f, 0.0f};
                z = __builtin_amdgcn_mfma_f32_16x16x32_bf16(kf[0][t], qf[mt][0], z, 0, 0, 0);
                st[mt][t] = __builtin_amdgcn_mfma_f32_16x16x32_bf16(kf[1][t], qf[mt][1], z, 0, 0, 0);
            }

        // ---- max-free softmax: p = exp2(s), per-lane l partials ----
        u32 pk[2][4][2];
#pragma unroll
        for (int mt = 0; mt < 2; ++mt) {
            f32x4 s4 = {0.0f, 0.0f, 0.0f, 0.0f};
#pragma unroll
            for (int t = 0; t < 4; ++t) {
                f32x4 p;
#pragma unroll
                for (int r = 0; r < 4; ++r) p[r] = exp2f(st[mt][t][r]);
                s4 += p;
                pk[mt][t][0] = pkbf(p[0], p[1]);
                pk[mt][t][1] = pkbf(p[2], p[3]);
            }
            l_i[mt] += s4[0] + s4[1] + s4[2] + s4[3];
        }

        // ---- O^T += V^T.P^T (permuted-k consistent on both operands) ----
#pragma unroll
        for (int cp = 0; cp < 2; ++cp) {
            union { bf16x8 v; u32 uw[4]; } pf0, pf1;
            pf0.uw[0] = pk[0][2 * cp][0];     pf0.uw[1] = pk[0][2 * cp][1];
            pf0.uw[2] = pk[0][2 * cp + 1][0]; pf0.uw[3] = pk[0][2 * cp + 1][1];
            pf1.uw[0] = pk[1][2 * cp][0];     pf1.uw[1] = pk[1][2 * cp][1];
            pf1.uw[2] = pk[1][2 * cp + 1][0]; pf1.uw[3] = pk[1][2 * cp + 1][1];
#pragma unroll
            for (int dt = 0; dt < 4; ++dt) {
                oacc[0][dt] = __builtin_amdgcn_mfma_f32_16x16x32_bf16(
                    vf[cp][dt].v, pf0.v, oacc[0][dt], 0, 0, 0);
                oacc[1][dt] = __builtin_amdgcn_mfma_f32_16x16x32_bf16(
                    vf[cp][dt].v, pf1.v, oacc[1][dt], 0, 0, 0);
            }
        }
    }

    // ---- cross-quad l reduction (once), /l, packed 8B stores ----
#pragma unroll
    for (int mt = 0; mt < 2; ++mt) {
        float l = l_i[mt];
        l += __shfl_xor(l, 16);
        l += __shfl_xor(l, 32);
        const float inv = 1.0f / l;
        const int lrow = l0 + w * 32 + mt * 16 + l15;
        u16* ob = out + ((size_t)(b * Lc + lrow)) * Dc + h * HDc;
#pragma unroll
        for (int dt = 0; dt < 4; ++dt) {
            uint2 pr;
            pr.x = pkbf(oacc[mt][dt][0] * inv, oacc[mt][dt][1] * inv);
            pr.y = pkbf(oacc[mt][dt][2] * inv, oacc[mt][dt][3] * inv);
            *(uint2*)&ob[dt * 16 + quad * 4] = pr;
        }
    }
}

// ---------------------------------------------------------------------------
// Output projection, SWAPPED (A=Wo features, B=attn tokens): regs run along
// features -> float4 (16B) contiguous stores into row-major (B,L,D) fp32.
// ---------------------------------------------------------------------------
__global__ __launch_bounds__(256) void gemm_o_bf16(
    const u16* __restrict__ Ab, const u16* __restrict__ Wob,
    const float* __restrict__ bo, float* __restrict__ out)
{
    __shared__ __attribute__((aligned(16))) u16 As[128 * 64];
    __shared__ __attribute__((aligned(16))) u16 Bs[128 * 64];
    const int row0 = blockIdx.y << 7;          // feature tile
    const int col0 = blockIdx.x << 7;          // token tile

    f32x4 acc[4][4];
#pragma unroll
    for (int i = 0; i < 4; ++i)
#pragma unroll
        for (int j = 0; j < 4; ++j)
#pragma unroll
            for (int r = 0; r < 4; ++r) acc[i][j][r] = 0.0f;

    gemm128_body(Wob, Ab, row0, col0, Dc, acc, As, Bs);

    const int tid = threadIdx.x;
    const int w = tid >> 6, lane = tid & 63;
    const int l15 = lane & 15, quad = lane >> 4;
    const int wm = (w & 1) << 6, wn = (w >> 1) << 6;

    float4 b4[4];
#pragma unroll
    for (int i = 0; i < 4; ++i)
        b4[i] = *(const float4*)&bo[row0 + wm + i * 16 + quad * 4];

#pragma unroll
    for (int j = 0; j < 4; ++j) {
        const int tok = col0 + wn + j * 16 + l15;
        float* obase = out + (size_t)tok * Dc + row0 + wm;
#pragma unroll
        for (int i = 0; i < 4; ++i) {
            float4 o;
            o.x = acc[i][j][0] + b4[i].x; o.y = acc[i][j][1] + b4[i].y;
            o.z = acc[i][j][2] + b4[i].z; o.w = acc[i][j][3] + b4[i].w;
            *(float4*)&obase[i * 16 + quad * 4] = o;
        }
    }
}

extern "C" void kernel_launch(void* const* d_in, const int* in_sizes, int n_in,
                              void* d_out, int out_size, void* d_ws, size_t ws_size,
                              hipStream_t stream)
{
    const float* query = (const float*)d_in[0];
    const float* Wq = (const float*)d_in[1];
    const float* bq = (const float*)d_in[2];
    const float* Wk = (const float*)d_in[3];
    const float* bk = (const float*)d_in[4];
    const float* Wv = (const float*)d_in[5];
    const float* bv = (const float*)d_in[6];
    const float* Wo = (const float*)d_in[7];
    const float* bo = (const float*)d_in[8];

    // ws layout (u16 elems): xb 4.19M | wq/wk/wv/wo 1.05M ea | q | k | vt | a
    u16* ws = (u16*)d_ws;
    const size_t nX = (size_t)Bc * Lc * Dc;      // 4,194,304
    const size_t nW = (size_t)Dc * Dc;           // 1,048,576
    u16* xb  = ws;
    u16* wqb = xb + nX;
    u16* wkb = wqb + nW;
    u16* wvb = wkb + nW;
    u16* wob = wvb + nW;
    u16* q_w = wob + nW;
    u16* k_w = q_w + nX;
    u16* vt_w = k_w + nX;
    u16* a_w = vt_w + nX;

    cast_bf16<<<dim3(8192), 256, 0, stream>>>(query, Wq, Wk, Wv, Wo,
                                              xb, wqb, wkb, wvb, wob);
    gemm_qkv_bf16<<<dim3(32, 8, 3), 256, 0, stream>>>(xb, wqb, wkb, wvb,
                                                      bq, bk, bv, q_w, k_w, vt_w);
    attn_mfma<<<dim3(512), 256, 0, stream>>>(q_w, k_w, vt_w, a_w);
    gemm_o_bf16<<<dim3(32, 8), 256, 0, stream>>>(a_w, wob, bo, (float*)d_out);
}

// Round 10
// 325.018 us; speedup vs baseline: 1.0102x; 1.0102x over previous
//
#include <hip/hip_runtime.h>

// B=2, L=2048, D=1024, H=16, HD=64.  All matmuls via bf16 MFMA (fp32 accum).
#define Bc 2
#define Lc 2048
#define Dc 1024
#define Hc 16
#define HDc 64
#define LOG2E 1.44269504088896340736f

typedef __bf16 bf16x8 __attribute__((ext_vector_type(8)));
typedef __bf16 bf16x2 __attribute__((ext_vector_type(2)));
typedef float f32x4 __attribute__((ext_vector_type(4)));
typedef unsigned short u16;
typedef unsigned int u32;
typedef unsigned long long u64;

// fp32 -> bf16 round-to-nearest-even
__device__ __forceinline__ u16 f2bf(float x) {
    union { float f; u32 u; } c; c.f = x;
    u32 u = c.u + 0x7fffu + ((c.u >> 16) & 1u);
    return (u16)(u >> 16);
}

// pack two fp32 -> bf16x2 in one u32 (low = a)
__device__ __forceinline__ u32 pkbf(float a, float b) {
#if __has_builtin(__builtin_amdgcn_cvt_pk_bf16_f32)
    union { bf16x2 v; u32 u; } c;
    c.v = __builtin_amdgcn_cvt_pk_bf16_f32(a, b);
    return c.u;
#else
    return (u32)f2bf(a) | ((u32)f2bf(b) << 16);
#endif
}

// async global->LDS, 16B/lane. LDS dest = wave-uniform base + lane*16 (m104).
__device__ __forceinline__ void g2l16(const void* g, void* l) {
    __builtin_amdgcn_global_load_lds(
        (const __attribute__((address_space(1))) void*)g,
        (__attribute__((address_space(3))) void*)l, 16, 0, 0);
}

// ---------------------------------------------------------------------------
// cast fp32 -> bf16: query (4096x1024) + Wq/Wk/Wv/Wo (1024x1024 each)
// ---------------------------------------------------------------------------
__global__ __launch_bounds__(256) void cast_bf16(
    const float* __restrict__ x,
    const float* __restrict__ wq, const float* __restrict__ wk,
    const float* __restrict__ wv, const float* __restrict__ wo,
    u16* __restrict__ xb, u16* __restrict__ wqb, u16* __restrict__ wkb,
    u16* __restrict__ wvb, u16* __restrict__ wob)
{
    const int i = blockIdx.x * 256 + threadIdx.x;   // float4 index
    const float* s; u16* d; int off;
    if (i < 1048576) { s = x; d = xb; off = i; }
    else {
        const int j = i - 1048576;
        const int sel = j >> 18;            // 0..3
        off = j & 262143;
        s = sel == 0 ? wq : sel == 1 ? wk : sel == 2 ? wv : wo;
        d = sel == 0 ? wqb : sel == 1 ? wkb : sel == 2 ? wvb : wob;
    }
    const float4 f = ((const float4*)s)[off];
    ushort4 o;
    o.x = f2bf(f.x); o.y = f2bf(f.y); o.z = f2bf(f.z); o.w = f2bf(f.w);
    ((ushort4*)d)[off] = o;
}

// ---------------------------------------------------------------------------
// 128x128-tile bf16 NT GEMM body, BK=64, XOR-swizzled LDS layout.
// R10: global->REG->LDS double-pump. The g2l16 path issues its loads between
// the two barriers (zero prefetch distance): barrier B's compiler-emitted
// s_waitcnt vmcnt(0) serially exposes full L2 latency every iter (17% MfmaUtil
// across R2-R8). Here tile i+1 is loaded into VGPRs AFTER barrier B, so the
// loads are in flight across the whole 32-MFMA compute phase; barrier A then
// drains an already-landed vmcnt, ds_write regs->LDS, and barrier B waits only
// on lgkm (cheap). Same swizzled bytes as g2l16 wrote -> read side unchanged.
// ---------------------------------------------------------------------------
__device__ __forceinline__ void gemm128_body(
    const u16* __restrict__ A, const u16* __restrict__ Bm,
    int row0, int col0, int K,
    f32x4 (&acc)[4][4], u16* As, u16* Bs)
{
    const int tid  = threadIdx.x;
    const int w    = tid >> 6;
    const int lane = tid & 63;
    const int l15  = lane & 15, quad = lane >> 4;
    const int srow = lane >> 3;                    // 0..7 row within 8-row chunk
    const int sxor = ((lane & 7) ^ srow) << 3;     // swizzled 16B unit (u16 idx)
    const int wm   = (w & 1) << 6, wn = (w >> 1) << 6;
    const int l7   = l15 & 7;
    const int lu   = (lane & 7) << 3;              // LDS unit offset (u16 idx)

    // prologue: prefetch tile 0 into registers
    uint4 ra[4], rbv[4];
#pragma unroll
    for (int s = 0; s < 4; ++s) {
        const int rr = w * 32 + s * 8 + srow;
        ra[s]  = *(const uint4*)&A [(size_t)(row0 + rr) * K + sxor];
        rbv[s] = *(const uint4*)&Bm[(size_t)(col0 + rr) * K + sxor];
    }

    for (int k0 = 0; k0 < K; k0 += 64) {
        __syncthreads();                   // barrier A: prior readers done;
                                           // vmcnt drain = loads issued a full
                                           // compute phase ago (latency hidden)
#pragma unroll
        for (int s = 0; s < 4; ++s) {
            const int rr = w * 32 + s * 8 + srow;
            *(uint4*)&As[rr * 64 + lu] = ra[s];
            *(uint4*)&Bs[rr * 64 + lu] = rbv[s];
        }
        __syncthreads();                   // barrier B: lgkm-only drain

        if (k0 + 64 < K) {                 // prefetch tile i+1 -> overlaps MFMA
#pragma unroll
            for (int s = 0; s < 4; ++s) {
                const int rr = w * 32 + s * 8 + srow;
                ra[s]  = *(const uint4*)&A [(size_t)(row0 + rr) * K + k0 + 64 + sxor];
                rbv[s] = *(const uint4*)&Bm[(size_t)(col0 + rr) * K + k0 + 64 + sxor];
            }
        }

#pragma unroll
        for (int kk = 0; kk < 2; ++kk) {
            bf16x8 af[4], bf[4];
#pragma unroll
            for (int i = 0; i < 4; ++i)
                af[i] = *(const bf16x8*)&As[(wm + i * 16 + l15) * 64 +
                                            (((kk * 4 + quad) ^ l7) << 3)];
#pragma unroll
            for (int j = 0; j < 4; ++j)
                bf[j] = *(const bf16x8*)&Bs[(wn + j * 16 + l15) * 64 +
                                            (((kk * 4 + quad) ^ l7) << 3)];
#pragma unroll
            for (int i = 0; i < 4; ++i)
#pragma unroll
                for (int j = 0; j < 4; ++j)
                    acc[i][j] = __builtin_amdgcn_mfma_f32_16x16x32_bf16(
                        af[i], bf[j], acc[i][j], 0, 0, 0);
        }
    }
}

// ---------------------------------------------------------------------------
// Fused QKV projection. grid (32, 8, 3): z selects {q,k,v}.
//   q/k: SWAPPED (A=W, B=X): regs = features -> (B,H,L,HD) contiguous hd.
//   v:   NORMAL  (A=X, B=Wv): regs = tokens -> (B,H,HD,L) contiguous l.
// q: *(0.125*log2e) folded (exp2-domain softmax).
// ---------------------------------------------------------------------------
__global__ __launch_bounds__(256) void gemm_qkv_bf16(
    const u16* __restrict__ Xb,
    const u16* __restrict__ Wqb, const u16* __restrict__ Wkb, const u16* __restrict__ Wvb,
    const float* __restrict__ bq, const float* __restrict__ bk, const float* __restrict__ bv,
    u16* __restrict__ qo, u16* __restrict__ ko, u16* __restrict__ vto)
{
    __shared__ __attribute__((aligned(16))) u16 As[128 * 64];
    __shared__ __attribute__((aligned(16))) u16 Bs[128 * 64];

    const int z = blockIdx.z;
    const int tid = threadIdx.x;
    const int w = tid >> 6, lane = tid & 63;
    const int l15 = lane & 15, quad = lane >> 4;
    const int wm = (w & 1) << 6, wn = (w >> 1) << 6;

    f32x4 acc[4][4];
#pragma unroll
    for (int i = 0; i < 4; ++i)
#pragma unroll
        for (int j = 0; j < 4; ++j)
#pragma unroll
            for (int r = 0; r < 4; ++r) acc[i][j][r] = 0.0f;

    if (z == 2) {
        // ---- v, NORMAL: A = X (tokens), B = Wv (features) ----
        const int row0 = blockIdx.x << 7;      // token tile
        const int col0 = blockIdx.y << 7;      // feature tile
        gemm128_body(Xb, Wvb, row0, col0, Dc, acc, As, Bs);

        const int b = row0 >> 11;              // 128-tile never crosses b
#pragma unroll
        for (int j = 0; j < 4; ++j) {
            const int n = col0 + wn + j * 16 + l15;   // feature
            const float bj = bv[n];
            const int hh = n >> 6, hd = n & 63;
            u16* vbase = vto + (((size_t)(b * Hc + hh) * HDc + hd) << 11);
#pragma unroll
            for (int i = 0; i < 4; ++i) {
                const int l = (row0 + wm + i * 16 + quad * 4) & (Lc - 1);
                uint2 pr;
                pr.x = pkbf(acc[i][j][0] + bj, acc[i][j][1] + bj);
                pr.y = pkbf(acc[i][j][2] + bj, acc[i][j][3] + bj);
                *(uint2*)&vbase[l] = pr;
            }
        }
        return;
    }

    // ---- q/k, SWAPPED: A = W (features), B = X (tokens) ----
    const u16*   W    = z == 0 ? Wqb : Wkb;
    const float* bias = z == 0 ? bq  : bk;
    u16*         outp = z == 0 ? qo  : ko;
    const int row0 = blockIdx.y << 7;          // feature tile
    const int col0 = blockIdx.x << 7;          // token tile
    gemm128_body(W, Xb, row0, col0, Dc, acc, As, Bs);

    const float qs = z == 0 ? 0.125f * LOG2E : 1.0f;   // HD^-0.5 * log2(e)
    const int h = (row0 + wm) >> 6;            // head const per quadrant
    float4 b4[4];
#pragma unroll
    for (int i = 0; i < 4; ++i)
        b4[i] = *(const float4*)&bias[row0 + wm + i * 16 + quad * 4];

#pragma unroll
    for (int j = 0; j < 4; ++j) {
        const int tok = col0 + wn + j * 16 + l15;
        const int bb = tok >> 11, ll = tok & (Lc - 1);
        u16* obase = outp + (((size_t)(bb * Hc + h) * Lc + ll) << 6);
#pragma unroll
        for (int i = 0; i < 4; ++i) {
            uint2 pr;
            pr.x = pkbf((acc[i][j][0] + b4[i].x) * qs, (acc[i][j][1] + b4[i].y) * qs);
            pr.y = pkbf((acc[i][j][2] + b4[i].z) * qs, (acc[i][j][3] + b4[i].w) * qs);
            *(uint2*)&obase[i * 16 + quad * 4] = pr;   // hd = i*16+quad*4
        }
    }
}

// ---------------------------------------------------------------------------
// Flash attention (exact R7/R8 81-us kernel, reverted from the R9 LDS-free
// regression: LDS staging is the CU's operand-broadcast mechanism; without it
// the kernel is VMEM-latency-bound at 182 us).
// S^T formulation, max-free softmax, wave owns 32 q-rows, grid 512 bh-fastest.
// ---------------------------------------------------------------------------
__global__ __launch_bounds__(256) void attn_mfma(
    const u16* __restrict__ q, const u16* __restrict__ k,
    const u16* __restrict__ vt, u16* __restrict__ out)
{
    __shared__ __attribute__((aligned(16))) u16 Ks[2][64 * 32]; // [d-pan][j][32 d]
    __shared__ __attribute__((aligned(16))) u16 Vs[2][64 * 32]; // [j-pan][d][32 j]

    const int tid = threadIdx.x;
    const int w = tid >> 6, lane = tid & 63;
    const int l15 = lane & 15, quad = lane >> 4;
    const int bh = blockIdx.x & 31;          // bh fastest: same-bh -> same XCD
    const int qt = blockIdx.x >> 5;          // 0..15
    const int h  = bh & (Hc - 1);
    const int b  = bh >> 4;
    const int l0 = qt << 7;                  // 128 q-rows per block

    const size_t bhs = (size_t)(b * Hc + h) * (Lc * HDc);
    const u16* qb = q  + bhs;
    const u16* kb = k  + bhs;
    const u16* vb = vt + bhs;            // [HD][L]

    bf16x8 qf[2][2];
#pragma unroll
    for (int mt = 0; mt < 2; ++mt) {
        const size_t row = (size_t)(l0 + w * 32 + mt * 16 + l15) * HDc;
        qf[mt][0] = *(const bf16x8*)&qb[row + quad * 8];
        qf[mt][1] = *(const bf16x8*)&qb[row + 32 + quad * 8];
    }

    const int srow  = lane >> 2;
    const int sunit = lane & 3;
    const int gd = (l15 >> 1) & 3;

    f32x4 oacc[2][4];
    float l_i[2] = {0.0f, 0.0f};
#pragma unroll
    for (int mt = 0; mt < 2; ++mt)
#pragma unroll
        for (int dt = 0; dt < 4; ++dt)
#pragma unroll
            for (int r = 0; r < 4; ++r) oacc[mt][dt][r] = 0.0f;

    for (int kt = 0; kt < Lc; kt += 64) {
        __syncthreads();
#pragma unroll
        for (int i = 0; i < 4; ++i) {
            const int c = w * 4 + i;
            const int p = (c >> 2) & 1, g = c & 3;
            const int row = g * 16 + srow;
            if (c < 8)
                g2l16(&kb[(size_t)(kt + row) * HDc + p * 32 +
                          ((sunit ^ ((row >> 1) & 3)) << 3)],
                      &Ks[p][g * 512]);
            else
                g2l16(&vb[(size_t)row * Lc + kt + p * 32 +
                          ((sunit ^ ((row >> 1) & 3)) << 3)],
                      &Vs[p][g * 512]);
        }
        __syncthreads();

        f32x4 st[2][4];
#pragma unroll
        for (int t = 0; t < 4; ++t) {
            const int j   = t * 16 + l15;
            const int off = j * 32 + ((quad ^ gd) << 3);
            const bf16x8 kf0 = *(const bf16x8*)&Ks[0][off];
            const bf16x8 kf1 = *(const bf16x8*)&Ks[1][off];
#pragma unroll
            for (int mt = 0; mt < 2; ++mt) {
                f32x4 z = {0.0f, 0.0f, 0.0f, 0.0f};
                z = __builtin_amdgcn_mfma_f32_16x16x32_bf16(kf0, qf[mt][0], z, 0, 0, 0);
                st[mt][t] = __builtin_amdgcn_mfma_f32_16x16x32_bf16(kf1, qf[mt][1], z, 0, 0, 0);
            }
        }

        u32 pk[2][4][2];
#pragma unroll
        for (int mt = 0; mt < 2; ++mt) {
            f32x4 s4 = {0.0f, 0.0f, 0.0f, 0.0f};
#pragma unroll
            for (int t = 0; t < 4; ++t) {
                f32x4 p;
#pragma unroll
                for (int r = 0; r < 4; ++r) p[r] = exp2f(st[mt][t][r]);
                s4 += p;
                pk[mt][t][0] = pkbf(p[0], p[1]);
                pk[mt][t][1] = pkbf(p[2], p[3]);
            }
            l_i[mt] += s4[0] + s4[1] + s4[2] + s4[3];
        }

#pragma unroll
        for (int cp = 0; cp < 2; ++cp) {
            union { bf16x8 v; u32 uw[4]; } pf0, pf1;
            pf0.uw[0] = pk[0][2 * cp][0];     pf0.uw[1] = pk[0][2 * cp][1];
            pf0.uw[2] = pk[0][2 * cp + 1][0]; pf0.uw[3] = pk[0][2 * cp + 1][1];
            pf1.uw[0] = pk[1][2 * cp][0];     pf1.uw[1] = pk[1][2 * cp][1];
            pf1.uw[2] = pk[1][2 * cp + 1][0]; pf1.uw[3] = pk[1][2 * cp + 1][1];
#pragma unroll
            for (int dt = 0; dt < 4; ++dt) {
                const int base = (dt * 16 + l15) * 32 + ((quad & 1) << 2);
                union { bf16x8 v; u64 d[2]; } vf;
                vf.d[0] = *(const u64*)&Vs[cp][base + (((quad >> 1) ^ gd) << 3)];
                vf.d[1] = *(const u64*)&Vs[cp][base + (((2 + (quad >> 1)) ^ gd) << 3)];
                oacc[0][dt] = __builtin_amdgcn_mfma_f32_16x16x32_bf16(
                    vf.v, pf0.v, oacc[0][dt], 0, 0, 0);
                oacc[1][dt] = __builtin_amdgcn_mfma_f32_16x16x32_bf16(
                    vf.v, pf1.v, oacc[1][dt], 0, 0, 0);
            }
        }
    }

#pragma unroll
    for (int mt = 0; mt < 2; ++mt) {
        float l = l_i[mt];
        l += __shfl_xor(l, 16);
        l += __shfl_xor(l, 32);
        const float inv = 1.0f / l;
        const int lrow = l0 + w * 32 + mt * 16 + l15;
        u16* ob = out + ((size_t)(b * Lc + lrow)) * Dc + h * HDc;
#pragma unroll
        for (int dt = 0; dt < 4; ++dt) {
            uint2 pr;
            pr.x = pkbf(oacc[mt][dt][0] * inv, oacc[mt][dt][1] * inv);
            pr.y = pkbf(oacc[mt][dt][2] * inv, oacc[mt][dt][3] * inv);
            *(uint2*)&ob[dt * 16 + quad * 4] = pr;
        }
    }
}

// ---------------------------------------------------------------------------
// Output projection, SWAPPED (A=Wo features, B=attn tokens): regs run along
// features -> float4 (16B) contiguous stores into row-major (B,L,D) fp32.
// ---------------------------------------------------------------------------
__global__ __launch_bounds__(256) void gemm_o_bf16(
    const u16* __restrict__ Ab, const u16* __restrict__ Wob,
    const float* __restrict__ bo, float* __restrict__ out)
{
    __shared__ __attribute__((aligned(16))) u16 As[128 * 64];
    __shared__ __attribute__((aligned(16))) u16 Bs[128 * 64];
    const int row0 = blockIdx.y << 7;          // feature tile
    const int col0 = blockIdx.x << 7;          // token tile

    f32x4 acc[4][4];
#pragma unroll
    for (int i = 0; i < 4; ++i)
#pragma unroll
        for (int j = 0; j < 4; ++j)
#pragma unroll
            for (int r = 0; r < 4; ++r) acc[i][j][r] = 0.0f;

    gemm128_body(Wob, Ab, row0, col0, Dc, acc, As, Bs);

    const int tid = threadIdx.x;
    const int w = tid >> 6, lane = tid & 63;
    const int l15 = lane & 15, quad = lane >> 4;
    const int wm = (w & 1) << 6, wn = (w >> 1) << 6;

    float4 b4[4];
#pragma unroll
    for (int i = 0; i < 4; ++i)
        b4[i] = *(const float4*)&bo[row0 + wm + i * 16 + quad * 4];

#pragma unroll
    for (int j = 0; j < 4; ++j) {
        const int tok = col0 + wn + j * 16 + l15;
        float* obase = out + (size_t)tok * Dc + row0 + wm;
#pragma unroll
        for (int i = 0; i < 4; ++i) {
            float4 o;
            o.x = acc[i][j][0] + b4[i].x; o.y = acc[i][j][1] + b4[i].y;
            o.z = acc[i][j][2] + b4[i].z; o.w = acc[i][j][3] + b4[i].w;
            *(float4*)&obase[i * 16 + quad * 4] = o;
        }
    }
}

extern "C" void kernel_launch(void* const* d_in, const int* in_sizes, int n_in,
                              void* d_out, int out_size, void* d_ws, size_t ws_size,
                              hipStream_t stream)
{
    const float* query = (const float*)d_in[0];
    const float* Wq = (const float*)d_in[1];
    const float* bq = (const float*)d_in[2];
    const float* Wk = (const float*)d_in[3];
    const float* bk = (const float*)d_in[4];
    const float* Wv = (const float*)d_in[5];
    const float* bv = (const float*)d_in[6];
    const float* Wo = (const float*)d_in[7];
    const float* bo = (const float*)d_in[8];

    // ws layout (u16 elems): xb 4.19M | wq/wk/wv/wo 1.05M ea | q | k | vt | a
    u16* ws = (u16*)d_ws;
    const size_t nX = (size_t)Bc * Lc * Dc;      // 4,194,304
    const size_t nW = (size_t)Dc * Dc;           // 1,048,576
    u16* xb  = ws;
    u16* wqb = xb + nX;
    u16* wkb = wqb + nW;
    u16* wvb = wkb + nW;
    u16* wob = wvb + nW;
    u16* q_w = wob + nW;
    u16* k_w = q_w + nX;
    u16* vt_w = k_w + nX;
    u16* a_w = vt_w + nX;

    cast_bf16<<<dim3(8192), 256, 0, stream>>>(query, Wq, Wk, Wv, Wo,
                                              xb, wqb, wkb, wvb, wob);
    gemm_qkv_bf16<<<dim3(32, 8, 3), 256, 0, stream>>>(xb, wqb, wkb, wvb,
                                                      bq, bk, bv, q_w, k_w, vt_w);
    attn_mfma<<<dim3(512), 256, 0, stream>>>(q_w, k_w, vt_w, a_w);
    gemm_o_bf16<<<dim3(32, 8), 256, 0, stream>>>(a_w, wob, bo, (float*)d_out);
}

// Round 11
// 222.401 us; speedup vs baseline: 1.4764x; 1.4614x over previous
//
#include <hip/hip_runtime.h>

// B=2, L=2048, D=1024, H=16, HD=64.  All matmuls via bf16 MFMA (fp32 accum).
#define Bc 2
#define Lc 2048
#define Dc 1024
#define Hc 16
#define HDc 64
#define LOG2E 1.44269504088896340736f

typedef __bf16 bf16x8 __attribute__((ext_vector_type(8)));
typedef __bf16 bf16x2 __attribute__((ext_vector_type(2)));
typedef float f32x4 __attribute__((ext_vector_type(4)));
typedef unsigned short u16;
typedef unsigned int u32;
typedef unsigned long long u64;

// fp32 -> bf16 round-to-nearest-even
__device__ __forceinline__ u16 f2bf(float x) {
    union { float f; u32 u; } c; c.f = x;
    u32 u = c.u + 0x7fffu + ((c.u >> 16) & 1u);
    return (u16)(u >> 16);
}

// pack two fp32 -> bf16x2 in one u32 (low = a)
__device__ __forceinline__ u32 pkbf(float a, float b) {
#if __has_builtin(__builtin_amdgcn_cvt_pk_bf16_f32)
    union { bf16x2 v; u32 u; } c;
    c.v = __builtin_amdgcn_cvt_pk_bf16_f32(a, b);
    return c.u;
#else
    return (u32)f2bf(a) | ((u32)f2bf(b) << 16);
#endif
}

// async global->LDS, 16B/lane. LDS dest = wave-uniform base + lane*16 (m104).
__device__ __forceinline__ void g2l16(const void* g, void* l) {
    __builtin_amdgcn_global_load_lds(
        (const __attribute__((address_space(1))) void*)g,
        (__attribute__((address_space(3))) void*)l, 16, 0, 0);
}

// ---------------------------------------------------------------------------
// cast fp32 -> bf16: query (4096x1024) + Wq/Wk/Wv/Wo (1024x1024 each)
// ---------------------------------------------------------------------------
__global__ __launch_bounds__(256) void cast_bf16(
    const float* __restrict__ x,
    const float* __restrict__ wq, const float* __restrict__ wk,
    const float* __restrict__ wv, const float* __restrict__ wo,
    u16* __restrict__ xb, u16* __restrict__ wqb, u16* __restrict__ wkb,
    u16* __restrict__ wvb, u16* __restrict__ wob)
{
    const int i = blockIdx.x * 256 + threadIdx.x;   // float4 index
    const float* s; u16* d; int off;
    if (i < 1048576) { s = x; d = xb; off = i; }
    else {
        const int j = i - 1048576;
        const int sel = j >> 18;            // 0..3
        off = j & 262143;
        s = sel == 0 ? wq : sel == 1 ? wk : sel == 2 ? wv : wo;
        d = sel == 0 ? wqb : sel == 1 ? wkb : sel == 2 ? wvb : wob;
    }
    const float4 f = ((const float4*)s)[off];
    ushort4 o;
    o.x = f2bf(f.x); o.y = f2bf(f.y); o.z = f2bf(f.z); o.w = f2bf(f.w);
    ((ushort4*)d)[off] = o;
}

// ---------------------------------------------------------------------------
// 128x128-tile bf16 NT GEMM body, BK=64, XOR-swizzled g2l16 staging.
// EXACT R8 version (revert of R10's reg double-pump, which spilled ra/rbv to
// scratch: WRITE_SIZE 24->170 MB, VALUBusy 5%, 2x slowdown. The m97-family
// 2-barrier structure has no register headroom for source-level pipelining.)
// ---------------------------------------------------------------------------
__device__ __forceinline__ void gemm128_body(
    const u16* __restrict__ A, const u16* __restrict__ Bm,
    int row0, int col0, int K,
    f32x4 (&acc)[4][4], u16* As, u16* Bs)
{
    const int tid  = threadIdx.x;
    const int w    = tid >> 6;
    const int lane = tid & 63;
    const int l15  = lane & 15, quad = lane >> 4;
    const int srow = lane >> 3;                    // 0..7 row within 8-row chunk
    const int sxor = ((lane & 7) ^ srow) << 3;     // swizzled 16B unit (u16 idx)
    const int wm   = (w & 1) << 6, wn = (w >> 1) << 6;
    const int l7   = l15 & 7;

    for (int k0 = 0; k0 < K; k0 += 64) {
        __syncthreads();                   // prior tile's readers done
#pragma unroll
        for (int s = 0; s < 4; ++s) {      // wave w stages rows [w*32, w*32+32)
            const int rb = w * 32 + s * 8;
            g2l16(&A [(size_t)(row0 + rb + srow) * K + k0 + sxor], &As[rb * 64]);
            g2l16(&Bm[(size_t)(col0 + rb + srow) * K + k0 + sxor], &Bs[rb * 64]);
        }
        __syncthreads();                   // vmcnt(0) drain before use

#pragma unroll
        for (int kk = 0; kk < 2; ++kk) {
            bf16x8 af[4], bf[4];
#pragma unroll
            for (int i = 0; i < 4; ++i)
                af[i] = *(const bf16x8*)&As[(wm + i * 16 + l15) * 64 +
                                            (((kk * 4 + quad) ^ l7) << 3)];
#pragma unroll
            for (int j = 0; j < 4; ++j)
                bf[j] = *(const bf16x8*)&Bs[(wn + j * 16 + l15) * 64 +
                                            (((kk * 4 + quad) ^ l7) << 3)];
#pragma unroll
            for (int i = 0; i < 4; ++i)
#pragma unroll
                for (int j = 0; j < 4; ++j)
                    acc[i][j] = __builtin_amdgcn_mfma_f32_16x16x32_bf16(
                        af[i], bf[j], acc[i][j], 0, 0, 0);
        }
    }
}

// ---------------------------------------------------------------------------
// Fused QKV projection (R8, frozen). grid (32, 8, 3): z selects {q,k,v}.
//   q/k: SWAPPED (A=W, B=X): regs = features -> (B,H,L,HD) contiguous hd.
//   v:   NORMAL  (A=X, B=Wv): regs = tokens -> (B,H,HD,L) contiguous l.
// q: *(0.125*log2e) folded (exp2-domain softmax).
// ---------------------------------------------------------------------------
__global__ __launch_bounds__(256) void gemm_qkv_bf16(
    const u16* __restrict__ Xb,
    const u16* __restrict__ Wqb, const u16* __restrict__ Wkb, const u16* __restrict__ Wvb,
    const float* __restrict__ bq, const float* __restrict__ bk, const float* __restrict__ bv,
    u16* __restrict__ qo, u16* __restrict__ ko, u16* __restrict__ vto)
{
    __shared__ __attribute__((aligned(16))) u16 As[128 * 64];
    __shared__ __attribute__((aligned(16))) u16 Bs[128 * 64];

    const int z = blockIdx.z;
    const int tid = threadIdx.x;
    const int w = tid >> 6, lane = tid & 63;
    const int l15 = lane & 15, quad = lane >> 4;
    const int wm = (w & 1) << 6, wn = (w >> 1) << 6;

    f32x4 acc[4][4];
#pragma unroll
    for (int i = 0; i < 4; ++i)
#pragma unroll
        for (int j = 0; j < 4; ++j)
#pragma unroll
            for (int r = 0; r < 4; ++r) acc[i][j][r] = 0.0f;

    if (z == 2) {
        // ---- v, NORMAL: A = X (tokens), B = Wv (features) ----
        const int row0 = blockIdx.x << 7;      // token tile
        const int col0 = blockIdx.y << 7;      // feature tile
        gemm128_body(Xb, Wvb, row0, col0, Dc, acc, As, Bs);

        const int b = row0 >> 11;              // 128-tile never crosses b
#pragma unroll
        for (int j = 0; j < 4; ++j) {
            const int n = col0 + wn + j * 16 + l15;   // feature
            const float bj = bv[n];
            const int hh = n >> 6, hd = n & 63;
            u16* vbase = vto + (((size_t)(b * Hc + hh) * HDc + hd) << 11);
#pragma unroll
            for (int i = 0; i < 4; ++i) {
                const int l = (row0 + wm + i * 16 + quad * 4) & (Lc - 1);
                uint2 pr;
                pr.x = pkbf(acc[i][j][0] + bj, acc[i][j][1] + bj);
                pr.y = pkbf(acc[i][j][2] + bj, acc[i][j][3] + bj);
                *(uint2*)&vbase[l] = pr;
            }
        }
        return;
    }

    // ---- q/k, SWAPPED: A = W (features), B = X (tokens) ----
    const u16*   W    = z == 0 ? Wqb : Wkb;
    const float* bias = z == 0 ? bq  : bk;
    u16*         outp = z == 0 ? qo  : ko;
    const int row0 = blockIdx.y << 7;          // feature tile
    const int col0 = blockIdx.x << 7;          // token tile
    gemm128_body(W, Xb, row0, col0, Dc, acc, As, Bs);

    const float qs = z == 0 ? 0.125f * LOG2E : 1.0f;   // HD^-0.5 * log2(e)
    const int h = (row0 + wm) >> 6;            // head const per quadrant
    float4 b4[4];
#pragma unroll
    for (int i = 0; i < 4; ++i)
        b4[i] = *(const float4*)&bias[row0 + wm + i * 16 + quad * 4];

#pragma unroll
    for (int j = 0; j < 4; ++j) {
        const int tok = col0 + wn + j * 16 + l15;
        const int bb = tok >> 11, ll = tok & (Lc - 1);
        u16* obase = outp + (((size_t)(bb * Hc + h) * Lc + ll) << 6);
#pragma unroll
        for (int i = 0; i < 4; ++i) {
            uint2 pr;
            pr.x = pkbf((acc[i][j][0] + b4[i].x) * qs, (acc[i][j][1] + b4[i].y) * qs);
            pr.y = pkbf((acc[i][j][2] + b4[i].z) * qs, (acc[i][j][3] + b4[i].w) * qs);
            *(uint2*)&obase[i * 16 + quad * 4] = pr;   // hd = i*16+quad*4
        }
    }
}

// ---------------------------------------------------------------------------
// Flash attention, S^T formulation, max-free softmax.
// R11: 128-key staging tile = TWO 64-key compute halves per barrier pair.
// Same per-half register footprint and inner code as R8; barrier pairs per
// block drop 32 -> 16. LDS 32KB single-buffered (2 blocks/CU unchanged).
// ---------------------------------------------------------------------------
__global__ __launch_bounds__(256) void attn_mfma(
    const u16* __restrict__ q, const u16* __restrict__ k,
    const u16* __restrict__ vt, u16* __restrict__ out)
{
    __shared__ __attribute__((aligned(16))) u16 Ks[2][128 * 32]; // [d-pan][j][32 d]
    __shared__ __attribute__((aligned(16))) u16 Vs[4][64 * 32];  // [j-pan][d][32 j]

    const int tid = threadIdx.x;
    const int w = tid >> 6, lane = tid & 63;
    const int l15 = lane & 15, quad = lane >> 4;
    const int bh = blockIdx.x & 31;          // bh fastest: same-bh -> same XCD
    const int qt = blockIdx.x >> 5;          // 0..15
    const int h  = bh & (Hc - 1);
    const int b  = bh >> 4;
    const int l0 = qt << 7;                  // 128 q-rows per block

    const size_t bhs = (size_t)(b * Hc + h) * (Lc * HDc);
    const u16* qb = q  + bhs;
    const u16* kb = k  + bhs;
    const u16* vb = vt + bhs;            // [HD][L]

    bf16x8 qf[2][2];
#pragma unroll
    for (int mt = 0; mt < 2; ++mt) {
        const size_t row = (size_t)(l0 + w * 32 + mt * 16 + l15) * HDc;
        qf[mt][0] = *(const bf16x8*)&qb[row + quad * 8];
        qf[mt][1] = *(const bf16x8*)&qb[row + 32 + quad * 8];
    }

    const int srow  = lane >> 2;
    const int sunit = lane & 3;
    const int gd = (l15 >> 1) & 3;

    f32x4 oacc[2][4];
    float l_i[2] = {0.0f, 0.0f};
#pragma unroll
    for (int mt = 0; mt < 2; ++mt)
#pragma unroll
        for (int dt = 0; dt < 4; ++dt)
#pragma unroll
            for (int r = 0; r < 4; ++r) oacc[mt][dt][r] = 0.0f;

    for (int kt = 0; kt < Lc; kt += 128) {
        __syncthreads();
        // stage K (16KB: 2 d-panels x 8 groups) + V (16KB: 4 j-panels x 4
        // groups) = 32 chunks, 8 per wave; XOR swizzle on global source.
#pragma unroll
        for (int i = 0; i < 8; ++i) {
            const int c = w * 8 + i;             // 0..31
            if (c < 16) {     // K chunk: row = key j in tile (0..127)
                const int p = c >> 3, g = c & 7;
                const int row = g * 16 + srow;
                g2l16(&kb[(size_t)(kt + row) * HDc + p * 32 +
                          ((sunit ^ ((row >> 1) & 3)) << 3)],
                      &Ks[p][g * 512]);
            } else {          // V chunk: row = d (0..63)
                const int cc = c - 16;
                const int cp = cc >> 2, g = cc & 3;
                const int row = g * 16 + srow;
                g2l16(&vb[(size_t)row * Lc + kt + cp * 32 +
                          ((sunit ^ ((row >> 1) & 3)) << 3)],
                      &Vs[cp][g * 512]);
            }
        }
        __syncthreads();

        // ---- two 64-key compute halves (same code/registers as R8) ----
#pragma unroll
        for (int hf = 0; hf < 2; ++hf) {
            f32x4 st[2][4];
#pragma unroll
            for (int t = 0; t < 4; ++t) {
                const int j   = (hf * 4 + t) * 16 + l15;
                const int off = j * 32 + ((quad ^ gd) << 3);
                const bf16x8 kf0 = *(const bf16x8*)&Ks[0][off];
                const bf16x8 kf1 = *(const bf16x8*)&Ks[1][off];
#pragma unroll
                for (int mt = 0; mt < 2; ++mt) {
                    f32x4 z = {0.0f, 0.0f, 0.0f, 0.0f};
                    z = __builtin_amdgcn_mfma_f32_16x16x32_bf16(kf0, qf[mt][0], z, 0, 0, 0);
                    st[mt][t] = __builtin_amdgcn_mfma_f32_16x16x32_bf16(kf1, qf[mt][1], z, 0, 0, 0);
                }
            }

            u32 pk[2][4][2];
#pragma unroll
            for (int mt = 0; mt < 2; ++mt) {
                f32x4 s4 = {0.0f, 0.0f, 0.0f, 0.0f};
#pragma unroll
                for (int t = 0; t < 4; ++t) {
                    f32x4 p;
#pragma unroll
                    for (int r = 0; r < 4; ++r) p[r] = exp2f(st[mt][t][r]);
                    s4 += p;
                    pk[mt][t][0] = pkbf(p[0], p[1]);
                    pk[mt][t][1] = pkbf(p[2], p[3]);
                }
                l_i[mt] += s4[0] + s4[1] + s4[2] + s4[3];
            }

#pragma unroll
            for (int cpl = 0; cpl < 2; ++cpl) {
                const int cp = hf * 2 + cpl;     // V panel (j-chunks 2cp,2cp+1)
                union { bf16x8 v; u32 uw[4]; } pf0, pf1;
                pf0.uw[0] = pk[0][2 * cpl][0];     pf0.uw[1] = pk[0][2 * cpl][1];
                pf0.uw[2] = pk[0][2 * cpl + 1][0]; pf0.uw[3] = pk[0][2 * cpl + 1][1];
                pf1.uw[0] = pk[1][2 * cpl][0];     pf1.uw[1] = pk[1][2 * cpl][1];
                pf1.uw[2] = pk[1][2 * cpl + 1][0]; pf1.uw[3] = pk[1][2 * cpl + 1][1];
#pragma unroll
                for (int dt = 0; dt < 4; ++dt) {
                    const int base = (dt * 16 + l15) * 32 + ((quad & 1) << 2);
                    union { bf16x8 v; u64 d[2]; } vf;
                    vf.d[0] = *(const u64*)&Vs[cp][base + (((quad >> 1) ^ gd) << 3)];
                    vf.d[1] = *(const u64*)&Vs[cp][base + (((2 + (quad >> 1)) ^ gd) << 3)];
                    oacc[0][dt] = __builtin_amdgcn_mfma_f32_16x16x32_bf16(
                        vf.v, pf0.v, oacc[0][dt], 0, 0, 0);
                    oacc[1][dt] = __builtin_amdgcn_mfma_f32_16x16x32_bf16(
                        vf.v, pf1.v, oacc[1][dt], 0, 0, 0);
                }
            }
        }
    }

#pragma unroll
    for (int mt = 0; mt < 2; ++mt) {
        float l = l_i[mt];
        l += __shfl_xor(l, 16);
        l += __shfl_xor(l, 32);
        const float inv = 1.0f / l;
        const int lrow = l0 + w * 32 + mt * 16 + l15;
        u16* ob = out + ((size_t)(b * Lc + lrow)) * Dc + h * HDc;
#pragma unroll
        for (int dt = 0; dt < 4; ++dt) {
            uint2 pr;
            pr.x = pkbf(oacc[mt][dt][0] * inv, oacc[mt][dt][1] * inv);
            pr.y = pkbf(oacc[mt][dt][2] * inv, oacc[mt][dt][3] * inv);
            *(uint2*)&ob[dt * 16 + quad * 4] = pr;
        }
    }
}

// ---------------------------------------------------------------------------
// Output projection (R8, frozen), SWAPPED: regs run along features -> float4
// contiguous stores into row-major (B,L,D) fp32. grid (32, 8).
// ---------------------------------------------------------------------------
__global__ __launch_bounds__(256) void gemm_o_bf16(
    const u16* __restrict__ Ab, const u16* __restrict__ Wob,
    const float* __restrict__ bo, float* __restrict__ out)
{
    __shared__ __attribute__((aligned(16))) u16 As[128 * 64];
    __shared__ __attribute__((aligned(16))) u16 Bs[128 * 64];
    const int row0 = blockIdx.y << 7;          // feature tile
    const int col0 = blockIdx.x << 7;          // token tile

    f32x4 acc[4][4];
#pragma unroll
    for (int i = 0; i < 4; ++i)
#pragma unroll
        for (int j = 0; j < 4; ++j)
#pragma unroll
            for (int r = 0; r < 4; ++r) acc[i][j][r] = 0.0f;

    gemm128_body(Wob, Ab, row0, col0, Dc, acc, As, Bs);

    const int tid = threadIdx.x;
    const int w = tid >> 6, lane = tid & 63;
    const int l15 = lane & 15, quad = lane >> 4;
    const int wm = (w & 1) << 6, wn = (w >> 1) << 6;

    float4 b4[4];
#pragma unroll
    for (int i = 0; i < 4; ++i)
        b4[i] = *(const float4*)&bo[row0 + wm + i * 16 + quad * 4];

#pragma unroll
    for (int j = 0; j < 4; ++j) {
        const int tok = col0 + wn + j * 16 + l15;
        float* obase = out + (size_t)tok * Dc + row0 + wm;
#pragma unroll
        for (int i = 0; i < 4; ++i) {
            float4 o;
            o.x = acc[i][j][0] + b4[i].x; o.y = acc[i][j][1] + b4[i].y;
            o.z = acc[i][j][2] + b4[i].z; o.w = acc[i][j][3] + b4[i].w;
            *(float4*)&obase[i * 16 + quad * 4] = o;
        }
    }
}

extern "C" void kernel_launch(void* const* d_in, const int* in_sizes, int n_in,
                              void* d_out, int out_size, void* d_ws, size_t ws_size,
                              hipStream_t stream)
{
    const float* query = (const float*)d_in[0];
    const float* Wq = (const float*)d_in[1];
    const float* bq = (const float*)d_in[2];
    const float* Wk = (const float*)d_in[3];
    const float* bk = (const float*)d_in[4];
    const float* Wv = (const float*)d_in[5];
    const float* bv = (const float*)d_in[6];
    const float* Wo = (const float*)d_in[7];
    const float* bo = (const float*)d_in[8];

    // ws layout (u16 elems): xb 4.19M | wq/wk/wv/wo 1.05M ea | q | k | vt | a
    u16* ws = (u16*)d_ws;
    const size_t nX = (size_t)Bc * Lc * Dc;      // 4,194,304
    const size_t nW = (size_t)Dc * Dc;           // 1,048,576
    u16* xb  = ws;
    u16* wqb = xb + nX;
    u16* wkb = wqb + nW;
    u16* wvb = wkb + nW;
    u16* wob = wvb + nW;
    u16* q_w = wob + nW;
    u16* k_w = q_w + nX;
    u16* vt_w = k_w + nX;
    u16* a_w = vt_w + nX;

    cast_bf16<<<dim3(8192), 256, 0, stream>>>(query, Wq, Wk, Wv, Wo,
                                              xb, wqb, wkb, wvb, wob);
    gemm_qkv_bf16<<<dim3(32, 8, 3), 256, 0, stream>>>(xb, wqb, wkb, wvb,
                                                      bq, bk, bv, q_w, k_w, vt_w);
    attn_mfma<<<dim3(512), 256, 0, stream>>>(q_w, k_w, vt_w, a_w);
    gemm_o_bf16<<<dim3(32, 8), 256, 0, stream>>>(a_w, wob, bo, (float*)d_out);
}